// Round 8
// baseline (660.942 us; speedup 1.0000x reference)
//
#include <hip/hip_runtime.h>
#include <hip/hip_bf16.h>

#define NF 128   // feature dim
#define PB 512   // pool partial blocks
#define GEMM_BLOCKS 512  // persistent-ish gemm grid
#define PART_SHIFT 9     // 512 nodes per coarse bucket
#define PART_NODES 512
#define PART_CHUNK 4096  // edges per partition block (256 thr x 16)

typedef __attribute__((ext_vector_type(8))) short bf16x8;
typedef __attribute__((ext_vector_type(4))) float f32x4;

__device__ inline float b2f(ushort u) { return __uint_as_float(((uint)u) << 16); }
__device__ inline ushort f2bf(float f) {           // round-to-nearest-even
  uint u = __float_as_uint(f);
  return (ushort)((u + 0x7fffu + ((u >> 16) & 1u)) >> 16);
}

// ---------------- x -> bf16 ----------------
__global__ __launch_bounds__(256) void k_cvt(const float* __restrict__ x,
                                             ushort* __restrict__ xb, int total4) {
  for (int i = blockIdx.x * 256 + threadIdx.x; i < total4; i += gridDim.x * 256) {
    float4 v = *(const float4*)&x[(size_t)i * 4];
    ushort4 o;
    o.x = f2bf(v.x); o.y = f2bf(v.y); o.z = f2bf(v.z); o.w = f2bf(v.w);
    *(ushort4*)&xb[(size_t)i * 4] = o;
  }
}

// ---------------- CSR build (atomic-free, chunk x bucket) ----------------
// phase 1: per-chunk LDS histogram over coarse buckets -> bcnt[chunk][256]
__global__ __launch_bounds__(256) void k_part1(const int* __restrict__ dst,
                                               int* __restrict__ bcnt, int E) {
  __shared__ int lhist[256];
  int t = threadIdx.x;
  int cb = blockIdx.x * PART_CHUNK;
  lhist[t] = 0;
  __syncthreads();
  #pragma unroll
  for (int i = 0; i < 16; i++) {
    int e = cb + i * 256 + t;
    if (e < E) atomicAdd(&lhist[dst[e] >> PART_SHIFT], 1);
  }
  __syncthreads();
  bcnt[blockIdx.x * 256 + t] = lhist[t];
}

// phase 2 (1 block): bucket totals -> exclusive scan -> bucket_start;
// per-chunk run bases cbase[chunk][bucket]; also row_start[n]=E.
__global__ __launch_bounds__(256) void k_bscan(const int* __restrict__ bcnt,
                                               int* __restrict__ cbase,
                                               int* __restrict__ bucket_start,
                                               int* __restrict__ row_start,
                                               int npart, int nbkt, int n, int E) {
  __shared__ int s[256];
  int t = threadIdx.x;
  int tot = 0;
  for (int c = 0; c < npart; c++) tot += bcnt[c * 256 + t];
  s[t] = tot;
  __syncthreads();
  for (int off = 1; off < 256; off <<= 1) {
    int u = (t >= off) ? s[t - off] : 0;
    __syncthreads();
    s[t] += u;
    __syncthreads();
  }
  int run = s[t] - tot;              // exclusive bucket prefix
  if (t < nbkt) bucket_start[t] = run;
  if (t == 0) { bucket_start[nbkt] = E; row_start[n] = E; }
  for (int c = 0; c < npart; c++) {
    cbase[c * 256 + t] = run;
    run += bcnt[c * 256 + t];
  }
}

// phase 3: LDS-ranked scatter into reserved runs (no global atomics);
// each 64B line of bkt written by ONE block; records packed to 4B.
__global__ __launch_bounds__(256) void k_part2(const int* __restrict__ src,
                                               const int* __restrict__ dst,
                                               const int* __restrict__ cbase,
                                               uint* __restrict__ bkt, int E) {
  __shared__ int lhist[256];
  __shared__ int lbase[256];
  int t = threadIdx.x;
  int cb = blockIdx.x * PART_CHUNK;
  lhist[t] = 0;
  __syncthreads();
  uint rec[16];
  short rb[16];
  short rr[16];
  #pragma unroll
  for (int i = 0; i < 16; i++) {
    int e = cb + i * 256 + t;
    if (e < E) {
      int s = src[e], d = dst[e];
      int b = d >> PART_SHIFT;
      rec[i] = ((uint)(d & (PART_NODES - 1)) << 17) | (uint)s;
      rb[i] = (short)b;
      rr[i] = (short)atomicAdd(&lhist[b], 1);
    } else rb[i] = -1;
  }
  __syncthreads();
  lbase[t] = cbase[blockIdx.x * 256 + t];
  __syncthreads();
  #pragma unroll
  for (int i = 0; i < 16; i++) {
    if (rb[i] >= 0) bkt[lbase[rb[i]] + (int)rr[i]] = rec[i];
  }
}

// phase 4: one block per bucket; LDS degree count + in-block scan ->
// row_start (coalesced) + LDS cursors; place col within the bucket window.
__global__ __launch_bounds__(256) void k_fill4(const uint* __restrict__ bkt,
                                               const int* __restrict__ bucket_start,
                                               int* __restrict__ row_start,
                                               int* __restrict__ col, int n) {
  __shared__ int dcnt[PART_NODES];
  __shared__ int s[256];
  __shared__ int cur[PART_NODES];
  int t = threadIdx.x;
  int base = blockIdx.x << PART_SHIFT;
  dcnt[2 * t] = 0; dcnt[2 * t + 1] = 0;
  __syncthreads();
  int ebeg = bucket_start[blockIdx.x], eend = bucket_start[blockIdx.x + 1];
  for (int j = ebeg + t; j < eend; j += 256)
    atomicAdd(&dcnt[bkt[j] >> 17], 1);
  __syncthreads();
  int d0 = dcnt[2 * t], d1 = dcnt[2 * t + 1];
  int pair = d0 + d1;
  s[t] = pair;
  __syncthreads();
  for (int off = 1; off < 256; off <<= 1) {
    int u = (t >= off) ? s[t - off] : 0;
    __syncthreads();
    s[t] += u;
    __syncthreads();
  }
  int pre = ebeg + s[t] - pair;      // exclusive within bucket
  cur[2 * t] = pre;
  cur[2 * t + 1] = pre + d0;
  if (base + 2 * t < n)     row_start[base + 2 * t]     = pre;
  if (base + 2 * t + 1 < n) row_start[base + 2 * t + 1] = pre + d0;
  __syncthreads();
  for (int j = ebeg + t; j < eend; j += 256) {
    uint r = bkt[j];
    int pos = atomicAdd(&cur[r >> 17], 1);
    col[pos] = (int)(r & 0x1FFFFu);
  }
}

// ---------------- gather-mean (bf16 in/out, fp32 accum) ----------------
// one wave per node; lane-split: half h (lane>>5) handles edges 2i+h, each
// lane owns 4 feats (8B loads -> 512B per instr across the wave); col indices
// prefetched 64-at-a-time and broadcast via shfl; 8 edges in flight.
__global__ __launch_bounds__(256) void k_aggr_bf(const ushort* __restrict__ h,
                                                 const int* __restrict__ row_start,
                                                 const int* __restrict__ col,
                                                 ushort* __restrict__ aggr, int n) {
  int gw = (blockIdx.x * 256 + threadIdx.x) >> 6;
  int lane = threadIdx.x & 63;
  if (gw >= n) return;
  int beg = row_start[gw], end = row_start[gw + 1];
  int half = lane >> 5, sl = lane & 31;
  const ushort* hbase = h + (size_t)sl * 4;
  float a0 = 0.f, a1 = 0.f, a2 = 0.f, a3 = 0.f;

  for (int cb = beg; cb < end; cb += 64) {
    int idx = cb + lane;
    int cv = (idx < end) ? col[idx] : 0;
    int m = min(64, end - cb);
    int j = 0;
    for (; j + 8 <= m; j += 8) {         // 4 pairs (8 edges) in flight
      uint2 v0, v1, v2, v3;
      int s0 = __shfl(cv, j + 0 + half);
      int s1 = __shfl(cv, j + 2 + half);
      int s2 = __shfl(cv, j + 4 + half);
      int s3 = __shfl(cv, j + 6 + half);
      v0 = *(const uint2*)&hbase[(size_t)s0 * NF];
      v1 = *(const uint2*)&hbase[(size_t)s1 * NF];
      v2 = *(const uint2*)&hbase[(size_t)s2 * NF];
      v3 = *(const uint2*)&hbase[(size_t)s3 * NF];
      a0 += __uint_as_float(v0.x << 16) + __uint_as_float(v1.x << 16) +
            __uint_as_float(v2.x << 16) + __uint_as_float(v3.x << 16);
      a1 += __uint_as_float(v0.x & 0xffff0000u) + __uint_as_float(v1.x & 0xffff0000u) +
            __uint_as_float(v2.x & 0xffff0000u) + __uint_as_float(v3.x & 0xffff0000u);
      a2 += __uint_as_float(v0.y << 16) + __uint_as_float(v1.y << 16) +
            __uint_as_float(v2.y << 16) + __uint_as_float(v3.y << 16);
      a3 += __uint_as_float(v0.y & 0xffff0000u) + __uint_as_float(v1.y & 0xffff0000u) +
            __uint_as_float(v2.y & 0xffff0000u) + __uint_as_float(v3.y & 0xffff0000u);
    }
    for (; j < m; j += 2) {              // tail pairs (possibly odd last edge)
      int e = j + half;
      int s = __shfl(cv, (e < m) ? e : 0);
      if (e < m) {
        uint2 v = *(const uint2*)&hbase[(size_t)s * NF];
        a0 += __uint_as_float(v.x << 16);
        a1 += __uint_as_float(v.x & 0xffff0000u);
        a2 += __uint_as_float(v.y << 16);
        a3 += __uint_as_float(v.y & 0xffff0000u);
      }
    }
  }
  // combine the two halves (feats identical, edge subsets disjoint)
  a0 += __shfl_xor(a0, 32);
  a1 += __shfl_xor(a1, 32);
  a2 += __shfl_xor(a2, 32);
  a3 += __shfl_xor(a3, 32);
  int d = end - beg;
  float inv = (d > 0) ? 1.0f / (float)d : 0.0f;
  if (half == 0) {
    uint2 o;
    o.x = (uint)f2bf(a0 * inv) | ((uint)f2bf(a1 * inv) << 16);
    o.y = (uint)f2bf(a2 * inv) | ((uint)f2bf(a3 * inv) << 16);
    *(uint2*)&aggr[(size_t)gw * NF + sl * 4] = o;
  }
}

// ---------------- MFMA GEMM: hout = relu([aggr|hin] @ [Wl;Wr] + b) ----------------
#define WSWZ(c, kbyte) (((c) << 9) + ((kbyte) ^ (((c) & 7) << 4)))

__global__ __launch_bounds__(256) void k_gemm_mfma(const ushort* __restrict__ aggr,
                                                   const ushort* __restrict__ hin,
                                                   ushort* __restrict__ hout,
                                                   const float* __restrict__ Wl,
                                                   const float* __restrict__ Wr,
                                                   const float* __restrict__ bias,
                                                   int n, int nslab) {
  __shared__ ushort Wt[128 * 256];   // [col][k] bf16, 64 KB, XOR-swizzled
  int t = threadIdx.x;
  for (int i = t; i < 128 * 128; i += 256) {
    int k = i >> 7, c = i & 127;
    *(ushort*)((char*)Wt + WSWZ(c, k * 2))         = f2bf(Wl[i]);
    *(ushort*)((char*)Wt + WSWZ(c, (k + 128) * 2)) = f2bf(Wr[i]);
  }
  __syncthreads();

  int wv = t >> 6, lane = t & 63;
  int c0 = wv * 32;
  int lrow = lane & 15, lhi = lane >> 4;

  bf16x8 bfrag[8][2];
  #pragma unroll
  for (int kc = 0; kc < 8; kc++)
    #pragma unroll
    for (int ct = 0; ct < 2; ct++) {
      int colv = c0 + ct * 16 + lrow;
      int kbyte = (kc * 32 + lhi * 8) * 2;
      bfrag[kc][ct] = *(const bf16x8*)((const char*)Wt + WSWZ(colv, kbyte));
    }
  float bv0 = bias[c0 + lrow], bv1 = bias[c0 + 16 + lrow];

  for (int sl = blockIdx.x; sl < nslab; sl += GEMM_BLOCKS) {
    int row0 = sl * 64;
    f32x4 acc[4][2];
    #pragma unroll
    for (int rt = 0; rt < 4; rt++)
      #pragma unroll
      for (int ct = 0; ct < 2; ct++) acc[rt][ct] = (f32x4){0.f, 0.f, 0.f, 0.f};

    #pragma unroll
    for (int kc = 0; kc < 8; kc++) {
      const ushort* Asrc = (kc < 4) ? aggr : hin;
      int k0 = (kc & 3) * 32 + lhi * 8;
      bf16x8 af[4];
      #pragma unroll
      for (int rt = 0; rt < 4; rt++) {
        int r = row0 + rt * 16 + lrow;
        if (r >= n) r = n - 1;
        af[rt] = *(const bf16x8*)&Asrc[(size_t)r * NF + k0];
      }
      #pragma unroll
      for (int rt = 0; rt < 4; rt++) {
        acc[rt][0] = __builtin_amdgcn_mfma_f32_16x16x32_bf16(af[rt], bfrag[kc][0], acc[rt][0], 0, 0, 0);
        acc[rt][1] = __builtin_amdgcn_mfma_f32_16x16x32_bf16(af[rt], bfrag[kc][1], acc[rt][1], 0, 0, 0);
      }
    }
    // C/D: col = lane&15, row = (lane>>4)*4 + reg   [m89-verified]
    #pragma unroll
    for (int rt = 0; rt < 4; rt++) {
      int rbase = row0 + rt * 16 + lhi * 4;
      #pragma unroll
      for (int r = 0; r < 4; r++) {
        int row = rbase + r;
        if (row < n) {
          hout[(size_t)row * NF + c0 + lrow]      = f2bf(fmaxf(acc[rt][0][r] + bv0, 0.f));
          hout[(size_t)row * NF + c0 + 16 + lrow] = f2bf(fmaxf(acc[rt][1][r] + bv1, 0.f));
        }
      }
    }
  }
}

// ---------------- pool + head ----------------
__global__ __launch_bounds__(128) void k_pool1(const ushort* __restrict__ h,
                                               float* __restrict__ partial, int n) {
  int f = threadIdx.x;
  float s = 0.f;
  for (int r = blockIdx.x; r < n; r += PB) s += b2f(h[(size_t)r * NF + f]);
  partial[blockIdx.x * NF + f] = s;
}

__global__ __launch_bounds__(128) void k_pool2(const float* __restrict__ partial,
                                               const float* __restrict__ Wg,
                                               const float* __restrict__ bg,
                                               float* __restrict__ out, int n) {
  __shared__ float g[NF];
  int f = threadIdx.x;
  float s = 0.f;
  for (int b = 0; b < PB; b++) s += partial[b * NF + f];
  g[f] = s / (float)n;
  __syncthreads();
  if (f < 64) {
    float z = bg[f];
    #pragma unroll 4
    for (int k = 0; k < NF; k++) z += g[k] * Wg[k * 64 + f];
    out[f] = 1.0f / (1.0f + expf(-z));
  }
}

// ---------------- launch ----------------
extern "C" void kernel_launch(void* const* d_in, const int* in_sizes, int n_in,
                              void* d_out, int out_size, void* d_ws, size_t ws_size,
                              hipStream_t stream) {
  const float* x   = (const float*)d_in[0];
  const int*   ei  = (const int*)d_in[1];
  const float* Wl1 = (const float*)d_in[2];
  const float* Wr1 = (const float*)d_in[3];
  const float* b1  = (const float*)d_in[4];
  const float* Wl2 = (const float*)d_in[5];
  const float* Wr2 = (const float*)d_in[6];
  const float* b2  = (const float*)d_in[7];
  const float* Wl3 = (const float*)d_in[8];
  const float* Wr3 = (const float*)d_in[9];
  const float* b3  = (const float*)d_in[10];
  const float* Wg  = (const float*)d_in[11];
  const float* bg  = (const float*)d_in[12];
  float* out = (float*)d_out;

  int n = in_sizes[0] / NF;      // 100000
  int E = in_sizes[1] / 2;       // 1600000
  const int* srcp = ei;
  const int* dstp = ei + E;

  char* w = (char*)d_ws;
  size_t off = 0;
  auto carve = [&](size_t bytes) -> void* {
    off = (off + 255) & ~(size_t)255;
    void* p = w + off;
    off += bytes;
    return p;
  };
  int nbkt  = (n + PART_NODES - 1) / PART_NODES;   // 196 coarse buckets
  int npart = (E + PART_CHUNK - 1) / PART_CHUNK;   // 391 chunks
  int*    col       = (int*)   carve((size_t)E * 4);
  int*    row_start = (int*)   carve((size_t)(n + 1) * 4);
  int*    bucket_start = (int*)carve((size_t)(nbkt + 1) * 4);
  int*    bcnt      = (int*)   carve((size_t)npart * 256 * 4);
  int*    cbase     = (int*)   carve((size_t)npart * 256 * 4);
  ushort* xb        = (ushort*)carve((size_t)n * NF * 2);
  ushort* aggr      = (ushort*)carve((size_t)n * NF * 2);
  ushort* ha        = (ushort*)carve((size_t)n * NF * 2);
  ushort* hb        = (ushort*)carve((size_t)n * NF * 2);
  float*  partial   = (float*) carve((size_t)PB * NF * 4);
  uint*   bkt       = (uint*)hb;   // 4B-packed staging aliases hb (dead until layer 2)

  int ag = (n + 3) / 4;
  int nslab = (n + 63) / 64;

  // convert x to bf16
  k_cvt<<<2048, 256, 0, stream>>>(x, xb, n * NF / 4);

  // CSR build: chunk-histogram -> scan -> reserved scatter -> bucket-local fill
  k_part1<<<npart, 256, 0, stream>>>(dstp, bcnt, E);
  k_bscan<<<1, 256, 0, stream>>>(bcnt, cbase, bucket_start, row_start, npart, nbkt, n, E);
  k_part2<<<npart, 256, 0, stream>>>(srcp, dstp, cbase, bkt, E);
  k_fill4<<<nbkt, 256, 0, stream>>>(bkt, bucket_start, row_start, col, n);

  // layer 1: xb -> ha
  k_aggr_bf<<<ag, 256, 0, stream>>>(xb, row_start, col, aggr, n);
  k_gemm_mfma<<<GEMM_BLOCKS, 256, 0, stream>>>(aggr, xb, ha, Wl1, Wr1, b1, n, nslab);
  // layer 2: ha -> hb
  k_aggr_bf<<<ag, 256, 0, stream>>>(ha, row_start, col, aggr, n);
  k_gemm_mfma<<<GEMM_BLOCKS, 256, 0, stream>>>(aggr, ha, hb, Wl2, Wr2, b2, n, nslab);
  // layer 3: hb -> ha
  k_aggr_bf<<<ag, 256, 0, stream>>>(hb, row_start, col, aggr, n);
  k_gemm_mfma<<<GEMM_BLOCKS, 256, 0, stream>>>(aggr, hb, ha, Wl3, Wr3, b3, n, nslab);

  // pool + head
  k_pool1<<<PB, 128, 0, stream>>>(ha, partial, n);
  k_pool2<<<1, 128, 0, stream>>>(partial, Wg, bg, out, n);
}

// Round 9
// 554.424 us; speedup vs baseline: 1.1921x; 1.1921x over previous
//
#include <hip/hip_runtime.h>
#include <hip/hip_bf16.h>

#define NF 128   // feature dim
#define PB 512   // pool partial blocks
#define GEMM_BLOCKS 512  // persistent-ish gemm grid
#define PART_SHIFT 9     // 512 nodes per coarse bucket
#define PART_NODES 512
#define PART_CHUNK 4096  // edges per partition block (256 thr x 16)

typedef __attribute__((ext_vector_type(8))) short bf16x8;
typedef __attribute__((ext_vector_type(4))) float f32x4;

__device__ inline float b2f(ushort u) { return __uint_as_float(((uint)u) << 16); }
__device__ inline ushort f2bf(float f) {           // round-to-nearest-even
  uint u = __float_as_uint(f);
  return (ushort)((u + 0x7fffu + ((u >> 16) & 1u)) >> 16);
}

// ---------------- x -> bf16 ----------------
__global__ __launch_bounds__(256) void k_cvt(const float* __restrict__ x,
                                             ushort* __restrict__ xb, int total4) {
  for (int i = blockIdx.x * 256 + threadIdx.x; i < total4; i += gridDim.x * 256) {
    float4 v = *(const float4*)&x[(size_t)i * 4];
    ushort4 o;
    o.x = f2bf(v.x); o.y = f2bf(v.y); o.z = f2bf(v.z); o.w = f2bf(v.w);
    *(ushort4*)&xb[(size_t)i * 4] = o;
  }
}

// ---------------- CSR build (atomic-free, chunk x bucket) ----------------
// phase 1: per-chunk LDS histogram over coarse buckets -> bcnt[chunk][256]
__global__ __launch_bounds__(256) void k_part1(const int* __restrict__ dst,
                                               int* __restrict__ bcnt, int E) {
  __shared__ int lhist[256];
  int t = threadIdx.x;
  int cb = blockIdx.x * PART_CHUNK;
  lhist[t] = 0;
  __syncthreads();
  #pragma unroll
  for (int i = 0; i < 16; i++) {
    int e = cb + i * 256 + t;
    if (e < E) atomicAdd(&lhist[dst[e] >> PART_SHIFT], 1);
  }
  __syncthreads();
  bcnt[blockIdx.x * 256 + t] = lhist[t];
}

// phase 2a: per-bucket column scan over chunks (256 blocks, parallel)
__global__ __launch_bounds__(256) void k_bscan1(const int* __restrict__ bcnt,
                                                int* __restrict__ cbase,
                                                int* __restrict__ btot, int npart) {
  __shared__ int s[256];
  int b = blockIdx.x;   // bucket
  int t = threadIdx.x;
  int base = 0;
  for (int seg = 0; seg * 256 < npart; seg++) {
    int c = seg * 256 + t;
    int v = (c < npart) ? bcnt[c * 256 + b] : 0;
    s[t] = v;
    __syncthreads();
    for (int off = 1; off < 256; off <<= 1) {
      int u = (t >= off) ? s[t - off] : 0;
      __syncthreads();
      s[t] += u;
      __syncthreads();
    }
    if (c < npart) cbase[c * 256 + b] = base + s[t] - v;  // chunk-exclusive, no bucket base
    base += s[255];
    __syncthreads();
  }
  if (t == 0) btot[b] = base;
}

// phase 2b (1 block, one 256-wide scan): bucket_start[0..256], row_start[n]=E
__global__ __launch_bounds__(256) void k_bscan2(const int* __restrict__ btot,
                                                int* __restrict__ bucket_start,
                                                int* __restrict__ row_start,
                                                int n, int E) {
  __shared__ int s[256];
  int t = threadIdx.x;
  int v = btot[t];
  s[t] = v;
  __syncthreads();
  for (int off = 1; off < 256; off <<= 1) {
    int u = (t >= off) ? s[t - off] : 0;
    __syncthreads();
    s[t] += u;
    __syncthreads();
  }
  bucket_start[t] = s[t] - v;            // exclusive prefix
  if (t == 255) bucket_start[256] = s[255];   // = E
  if (t == 0) row_start[n] = E;
}

// phase 3: LDS-ranked scatter into reserved runs (no global atomics);
// each 64B line of bkt written by ONE block; records packed to 4B.
__global__ __launch_bounds__(256) void k_part2(const int* __restrict__ src,
                                               const int* __restrict__ dst,
                                               const int* __restrict__ cbase,
                                               const int* __restrict__ bucket_start,
                                               uint* __restrict__ bkt, int E) {
  __shared__ int lhist[256];
  __shared__ int lbase[256];
  int t = threadIdx.x;
  int cb = blockIdx.x * PART_CHUNK;
  lhist[t] = 0;
  __syncthreads();
  uint rec[16];
  short rb[16];
  short rr[16];
  #pragma unroll
  for (int i = 0; i < 16; i++) {
    int e = cb + i * 256 + t;
    if (e < E) {
      int s = src[e], d = dst[e];
      int b = d >> PART_SHIFT;
      rec[i] = ((uint)(d & (PART_NODES - 1)) << 17) | (uint)s;
      rb[i] = (short)b;
      rr[i] = (short)atomicAdd(&lhist[b], 1);
    } else rb[i] = -1;
  }
  __syncthreads();
  lbase[t] = cbase[blockIdx.x * 256 + t] + bucket_start[t];
  __syncthreads();
  #pragma unroll
  for (int i = 0; i < 16; i++) {
    if (rb[i] >= 0) bkt[lbase[rb[i]] + (int)rr[i]] = rec[i];
  }
}

// phase 4: one block per bucket; LDS degree count + in-block scan ->
// row_start (coalesced) + LDS cursors; place col within the bucket window.
__global__ __launch_bounds__(256) void k_fill4(const uint* __restrict__ bkt,
                                               const int* __restrict__ bucket_start,
                                               int* __restrict__ row_start,
                                               int* __restrict__ col, int n) {
  __shared__ int dcnt[PART_NODES];
  __shared__ int s[256];
  __shared__ int cur[PART_NODES];
  int t = threadIdx.x;
  int base = blockIdx.x << PART_SHIFT;
  dcnt[2 * t] = 0; dcnt[2 * t + 1] = 0;
  __syncthreads();
  int ebeg = bucket_start[blockIdx.x], eend = bucket_start[blockIdx.x + 1];
  for (int j = ebeg + t; j < eend; j += 256)
    atomicAdd(&dcnt[bkt[j] >> 17], 1);
  __syncthreads();
  int d0 = dcnt[2 * t], d1 = dcnt[2 * t + 1];
  int pair = d0 + d1;
  s[t] = pair;
  __syncthreads();
  for (int off = 1; off < 256; off <<= 1) {
    int u = (t >= off) ? s[t - off] : 0;
    __syncthreads();
    s[t] += u;
    __syncthreads();
  }
  int pre = ebeg + s[t] - pair;      // exclusive within bucket
  cur[2 * t] = pre;
  cur[2 * t + 1] = pre + d0;
  if (base + 2 * t < n)     row_start[base + 2 * t]     = pre;
  if (base + 2 * t + 1 < n) row_start[base + 2 * t + 1] = pre + d0;
  __syncthreads();
  for (int j = ebeg + t; j < eend; j += 256) {
    uint r = bkt[j];
    int pos = atomicAdd(&cur[r >> 17], 1);
    col[pos] = (int)(r & 0x1FFFFu);
  }
}

// ---------------- gather-mean (bf16 in/out, fp32 accum) ----------------
// one wave per node; lane-split: half h (lane>>5) handles edges 2i+h, each
// lane owns 4 feats (8B loads -> 512B per instr across the wave); col indices
// prefetched 64-at-a-time and broadcast via shfl; 8 edges in flight.
__global__ __launch_bounds__(256) void k_aggr_bf(const ushort* __restrict__ h,
                                                 const int* __restrict__ row_start,
                                                 const int* __restrict__ col,
                                                 ushort* __restrict__ aggr, int n) {
  int gw = (blockIdx.x * 256 + threadIdx.x) >> 6;
  int lane = threadIdx.x & 63;
  if (gw >= n) return;
  int beg = row_start[gw], end = row_start[gw + 1];
  int half = lane >> 5, sl = lane & 31;
  const ushort* hbase = h + (size_t)sl * 4;
  float a0 = 0.f, a1 = 0.f, a2 = 0.f, a3 = 0.f;

  for (int cb = beg; cb < end; cb += 64) {
    int idx = cb + lane;
    int cv = (idx < end) ? col[idx] : 0;
    int m = min(64, end - cb);
    int j = 0;
    for (; j + 8 <= m; j += 8) {         // 4 pairs (8 edges) in flight
      uint2 v0, v1, v2, v3;
      int s0 = __shfl(cv, j + 0 + half);
      int s1 = __shfl(cv, j + 2 + half);
      int s2 = __shfl(cv, j + 4 + half);
      int s3 = __shfl(cv, j + 6 + half);
      v0 = *(const uint2*)&hbase[(size_t)s0 * NF];
      v1 = *(const uint2*)&hbase[(size_t)s1 * NF];
      v2 = *(const uint2*)&hbase[(size_t)s2 * NF];
      v3 = *(const uint2*)&hbase[(size_t)s3 * NF];
      a0 += __uint_as_float(v0.x << 16) + __uint_as_float(v1.x << 16) +
            __uint_as_float(v2.x << 16) + __uint_as_float(v3.x << 16);
      a1 += __uint_as_float(v0.x & 0xffff0000u) + __uint_as_float(v1.x & 0xffff0000u) +
            __uint_as_float(v2.x & 0xffff0000u) + __uint_as_float(v3.x & 0xffff0000u);
      a2 += __uint_as_float(v0.y << 16) + __uint_as_float(v1.y << 16) +
            __uint_as_float(v2.y << 16) + __uint_as_float(v3.y << 16);
      a3 += __uint_as_float(v0.y & 0xffff0000u) + __uint_as_float(v1.y & 0xffff0000u) +
            __uint_as_float(v2.y & 0xffff0000u) + __uint_as_float(v3.y & 0xffff0000u);
    }
    for (; j < m; j += 2) {              // tail pairs (possibly odd last edge)
      int e = j + half;
      int s = __shfl(cv, (e < m) ? e : 0);
      if (e < m) {
        uint2 v = *(const uint2*)&hbase[(size_t)s * NF];
        a0 += __uint_as_float(v.x << 16);
        a1 += __uint_as_float(v.x & 0xffff0000u);
        a2 += __uint_as_float(v.y << 16);
        a3 += __uint_as_float(v.y & 0xffff0000u);
      }
    }
  }
  // combine the two halves (feats identical, edge subsets disjoint)
  a0 += __shfl_xor(a0, 32);
  a1 += __shfl_xor(a1, 32);
  a2 += __shfl_xor(a2, 32);
  a3 += __shfl_xor(a3, 32);
  int d = end - beg;
  float inv = (d > 0) ? 1.0f / (float)d : 0.0f;
  if (half == 0) {
    uint2 o;
    o.x = (uint)f2bf(a0 * inv) | ((uint)f2bf(a1 * inv) << 16);
    o.y = (uint)f2bf(a2 * inv) | ((uint)f2bf(a3 * inv) << 16);
    *(uint2*)&aggr[(size_t)gw * NF + sl * 4] = o;
  }
}

// ---------------- MFMA GEMM: hout = relu([aggr|hin] @ [Wl;Wr] + b) ----------------
#define WSWZ(c, kbyte) (((c) << 9) + ((kbyte) ^ (((c) & 7) << 4)))

__global__ __launch_bounds__(256) void k_gemm_mfma(const ushort* __restrict__ aggr,
                                                   const ushort* __restrict__ hin,
                                                   ushort* __restrict__ hout,
                                                   const float* __restrict__ Wl,
                                                   const float* __restrict__ Wr,
                                                   const float* __restrict__ bias,
                                                   int n, int nslab) {
  __shared__ ushort Wt[128 * 256];   // [col][k] bf16, 64 KB, XOR-swizzled
  int t = threadIdx.x;
  for (int i = t; i < 128 * 128; i += 256) {
    int k = i >> 7, c = i & 127;
    *(ushort*)((char*)Wt + WSWZ(c, k * 2))         = f2bf(Wl[i]);
    *(ushort*)((char*)Wt + WSWZ(c, (k + 128) * 2)) = f2bf(Wr[i]);
  }
  __syncthreads();

  int wv = t >> 6, lane = t & 63;
  int c0 = wv * 32;
  int lrow = lane & 15, lhi = lane >> 4;

  bf16x8 bfrag[8][2];
  #pragma unroll
  for (int kc = 0; kc < 8; kc++)
    #pragma unroll
    for (int ct = 0; ct < 2; ct++) {
      int colv = c0 + ct * 16 + lrow;
      int kbyte = (kc * 32 + lhi * 8) * 2;
      bfrag[kc][ct] = *(const bf16x8*)((const char*)Wt + WSWZ(colv, kbyte));
    }
  float bv0 = bias[c0 + lrow], bv1 = bias[c0 + 16 + lrow];

  for (int sl = blockIdx.x; sl < nslab; sl += GEMM_BLOCKS) {
    int row0 = sl * 64;
    f32x4 acc[4][2];
    #pragma unroll
    for (int rt = 0; rt < 4; rt++)
      #pragma unroll
      for (int ct = 0; ct < 2; ct++) acc[rt][ct] = (f32x4){0.f, 0.f, 0.f, 0.f};

    #pragma unroll
    for (int kc = 0; kc < 8; kc++) {
      const ushort* Asrc = (kc < 4) ? aggr : hin;
      int k0 = (kc & 3) * 32 + lhi * 8;
      bf16x8 af[4];
      #pragma unroll
      for (int rt = 0; rt < 4; rt++) {
        int r = row0 + rt * 16 + lrow;
        if (r >= n) r = n - 1;
        af[rt] = *(const bf16x8*)&Asrc[(size_t)r * NF + k0];
      }
      #pragma unroll
      for (int rt = 0; rt < 4; rt++) {
        acc[rt][0] = __builtin_amdgcn_mfma_f32_16x16x32_bf16(af[rt], bfrag[kc][0], acc[rt][0], 0, 0, 0);
        acc[rt][1] = __builtin_amdgcn_mfma_f32_16x16x32_bf16(af[rt], bfrag[kc][1], acc[rt][1], 0, 0, 0);
      }
    }
    // C/D: col = lane&15, row = (lane>>4)*4 + reg   [m89-verified]
    #pragma unroll
    for (int rt = 0; rt < 4; rt++) {
      int rbase = row0 + rt * 16 + lhi * 4;
      #pragma unroll
      for (int r = 0; r < 4; r++) {
        int row = rbase + r;
        if (row < n) {
          hout[(size_t)row * NF + c0 + lrow]      = f2bf(fmaxf(acc[rt][0][r] + bv0, 0.f));
          hout[(size_t)row * NF + c0 + 16 + lrow] = f2bf(fmaxf(acc[rt][1][r] + bv1, 0.f));
        }
      }
    }
  }
}

// ---------------- pool + head ----------------
__global__ __launch_bounds__(128) void k_pool1(const ushort* __restrict__ h,
                                               float* __restrict__ partial, int n) {
  int f = threadIdx.x;
  float s = 0.f;
  for (int r = blockIdx.x; r < n; r += PB) s += b2f(h[(size_t)r * NF + f]);
  partial[blockIdx.x * NF + f] = s;
}

__global__ __launch_bounds__(128) void k_pool2(const float* __restrict__ partial,
                                               const float* __restrict__ Wg,
                                               const float* __restrict__ bg,
                                               float* __restrict__ out, int n) {
  __shared__ float g[NF];
  int f = threadIdx.x;
  float s = 0.f;
  for (int b = 0; b < PB; b++) s += partial[b * NF + f];
  g[f] = s / (float)n;
  __syncthreads();
  if (f < 64) {
    float z = bg[f];
    #pragma unroll 4
    for (int k = 0; k < NF; k++) z += g[k] * Wg[k * 64 + f];
    out[f] = 1.0f / (1.0f + expf(-z));
  }
}

// ---------------- launch ----------------
extern "C" void kernel_launch(void* const* d_in, const int* in_sizes, int n_in,
                              void* d_out, int out_size, void* d_ws, size_t ws_size,
                              hipStream_t stream) {
  const float* x   = (const float*)d_in[0];
  const int*   ei  = (const int*)d_in[1];
  const float* Wl1 = (const float*)d_in[2];
  const float* Wr1 = (const float*)d_in[3];
  const float* b1  = (const float*)d_in[4];
  const float* Wl2 = (const float*)d_in[5];
  const float* Wr2 = (const float*)d_in[6];
  const float* b2  = (const float*)d_in[7];
  const float* Wl3 = (const float*)d_in[8];
  const float* Wr3 = (const float*)d_in[9];
  const float* b3  = (const float*)d_in[10];
  const float* Wg  = (const float*)d_in[11];
  const float* bg  = (const float*)d_in[12];
  float* out = (float*)d_out;

  int n = in_sizes[0] / NF;      // 100000
  int E = in_sizes[1] / 2;       // 1600000
  const int* srcp = ei;
  const int* dstp = ei + E;

  char* w = (char*)d_ws;
  size_t off = 0;
  auto carve = [&](size_t bytes) -> void* {
    off = (off + 255) & ~(size_t)255;
    void* p = w + off;
    off += bytes;
    return p;
  };
  int nbkt  = (n + PART_NODES - 1) / PART_NODES;   // 196 coarse buckets
  int npart = (E + PART_CHUNK - 1) / PART_CHUNK;   // 391 chunks
  int*    col       = (int*)   carve((size_t)E * 4);
  int*    row_start = (int*)   carve((size_t)(n + 1) * 4);
  int*    bucket_start = (int*)carve((size_t)257 * 4);
  int*    btot      = (int*)   carve((size_t)256 * 4);
  int*    bcnt      = (int*)   carve((size_t)npart * 256 * 4);
  int*    cbase     = (int*)   carve((size_t)npart * 256 * 4);
  ushort* xb        = (ushort*)carve((size_t)n * NF * 2);
  ushort* aggr      = (ushort*)carve((size_t)n * NF * 2);
  ushort* ha        = (ushort*)carve((size_t)n * NF * 2);
  ushort* hb        = (ushort*)carve((size_t)n * NF * 2);
  float*  partial   = (float*) carve((size_t)PB * NF * 4);
  uint*   bkt       = (uint*)hb;   // 4B-packed staging aliases hb (dead until layer 2)

  int ag = (n + 3) / 4;
  int nslab = (n + 63) / 64;

  // convert x to bf16
  k_cvt<<<2048, 256, 0, stream>>>(x, xb, n * NF / 4);

  // CSR build: chunk-histogram -> parallel 2D scan -> reserved scatter -> bucket-local fill
  k_part1<<<npart, 256, 0, stream>>>(dstp, bcnt, E);
  k_bscan1<<<256, 256, 0, stream>>>(bcnt, cbase, btot, npart);
  k_bscan2<<<1, 256, 0, stream>>>(btot, bucket_start, row_start, n, E);
  k_part2<<<npart, 256, 0, stream>>>(srcp, dstp, cbase, bucket_start, bkt, E);
  k_fill4<<<nbkt, 256, 0, stream>>>(bkt, bucket_start, row_start, col, n);

  // layer 1: xb -> ha
  k_aggr_bf<<<ag, 256, 0, stream>>>(xb, row_start, col, aggr, n);
  k_gemm_mfma<<<GEMM_BLOCKS, 256, 0, stream>>>(aggr, xb, ha, Wl1, Wr1, b1, n, nslab);
  // layer 2: ha -> hb
  k_aggr_bf<<<ag, 256, 0, stream>>>(ha, row_start, col, aggr, n);
  k_gemm_mfma<<<GEMM_BLOCKS, 256, 0, stream>>>(aggr, ha, hb, Wl2, Wr2, b2, n, nslab);
  // layer 3: hb -> ha
  k_aggr_bf<<<ag, 256, 0, stream>>>(hb, row_start, col, aggr, n);
  k_gemm_mfma<<<GEMM_BLOCKS, 256, 0, stream>>>(aggr, hb, ha, Wl3, Wr3, b3, n, nslab);

  // pool + head
  k_pool1<<<PB, 128, 0, stream>>>(ha, partial, n);
  k_pool2<<<1, 128, 0, stream>>>(partial, Wg, bg, out, n);
}

// Round 10
// 508.899 us; speedup vs baseline: 1.2988x; 1.0895x over previous
//
#include <hip/hip_runtime.h>
#include <hip/hip_bf16.h>

#define NF 128   // feature dim
#define PB 512   // pool partial blocks
#define GEMM_BLOCKS 512  // persistent-ish gemm grid
#define PART_SHIFT 9     // 512 nodes per coarse bucket
#define PART_NODES 512
#define PART_CHUNK 4096  // edges per partition block (256 thr x 16)

typedef __attribute__((ext_vector_type(8))) short bf16x8;
typedef __attribute__((ext_vector_type(4))) float f32x4;

__device__ inline float b2f(ushort u) { return __uint_as_float(((uint)u) << 16); }
__device__ inline ushort f2bf(float f) {           // round-to-nearest-even
  uint u = __float_as_uint(f);
  return (ushort)((u + 0x7fffu + ((u >> 16) & 1u)) >> 16);
}

// ---------------- x -> bf16 ----------------
__global__ __launch_bounds__(256) void k_cvt(const float* __restrict__ x,
                                             ushort* __restrict__ xb, int total4) {
  for (int i = blockIdx.x * 256 + threadIdx.x; i < total4; i += gridDim.x * 256) {
    float4 v = *(const float4*)&x[(size_t)i * 4];
    ushort4 o;
    o.x = f2bf(v.x); o.y = f2bf(v.y); o.z = f2bf(v.z); o.w = f2bf(v.w);
    *(ushort4*)&xb[(size_t)i * 4] = o;
  }
}

// ---------------- weight prep: [k][c] f32 x2 -> [c][k 0..255] bf16 ----------------
// block = (layer, col); thread = k. Writes coalesced 512B rows.
__global__ __launch_bounds__(256) void k_wprep(const float* __restrict__ Wl1,
                                               const float* __restrict__ Wr1,
                                               const float* __restrict__ Wl2,
                                               const float* __restrict__ Wr2,
                                               const float* __restrict__ Wl3,
                                               const float* __restrict__ Wr3,
                                               ushort* __restrict__ Wtg) {
  int l = blockIdx.x >> 7;          // layer 0..2
  int c = blockIdx.x & 127;         // col
  int k = threadIdx.x;              // 0..255
  const float* Wl = (l == 0) ? Wl1 : (l == 1) ? Wl2 : Wl3;
  const float* Wr = (l == 0) ? Wr1 : (l == 1) ? Wr2 : Wr3;
  float v = (k < 128) ? Wl[k * NF + c] : Wr[(k - 128) * NF + c];
  Wtg[((size_t)l * NF + c) * 256 + k] = f2bf(v);
}

// ---------------- CSR build (atomic-free, chunk x bucket) ----------------
__global__ __launch_bounds__(256) void k_part1(const int* __restrict__ dst,
                                               int* __restrict__ bcnt, int E) {
  __shared__ int lhist[256];
  int t = threadIdx.x;
  int cb = blockIdx.x * PART_CHUNK;
  lhist[t] = 0;
  __syncthreads();
  #pragma unroll
  for (int i = 0; i < 16; i++) {
    int e = cb + i * 256 + t;
    if (e < E) atomicAdd(&lhist[dst[e] >> PART_SHIFT], 1);
  }
  __syncthreads();
  bcnt[blockIdx.x * 256 + t] = lhist[t];
}

// per-bucket column scan over chunks (256 blocks, parallel)
__global__ __launch_bounds__(256) void k_bscan1(const int* __restrict__ bcnt,
                                                int* __restrict__ cbase,
                                                int* __restrict__ btot, int npart) {
  __shared__ int s[256];
  int b = blockIdx.x;   // bucket
  int t = threadIdx.x;
  int base = 0;
  for (int seg = 0; seg * 256 < npart; seg++) {
    int c = seg * 256 + t;
    int v = (c < npart) ? bcnt[c * 256 + b] : 0;
    s[t] = v;
    __syncthreads();
    for (int off = 1; off < 256; off <<= 1) {
      int u = (t >= off) ? s[t - off] : 0;
      __syncthreads();
      s[t] += u;
      __syncthreads();
    }
    if (c < npart) cbase[c * 256 + b] = base + s[t] - v;  // chunk-exclusive, no bucket base
    base += s[255];
    __syncthreads();
  }
  if (t == 0) btot[b] = base;
}

// 1 block: bucket_start[0..256], row_start[n]=E
__global__ __launch_bounds__(256) void k_bscan2(const int* __restrict__ btot,
                                                int* __restrict__ bucket_start,
                                                int* __restrict__ row_start,
                                                int n, int E) {
  __shared__ int s[256];
  int t = threadIdx.x;
  int v = btot[t];
  s[t] = v;
  __syncthreads();
  for (int off = 1; off < 256; off <<= 1) {
    int u = (t >= off) ? s[t - off] : 0;
    __syncthreads();
    s[t] += u;
    __syncthreads();
  }
  bucket_start[t] = s[t] - v;            // exclusive prefix
  if (t == 255) bucket_start[256] = s[255];   // = E
  if (t == 0) row_start[n] = E;
}

// LDS-ranked scatter into reserved runs (no global atomics)
__global__ __launch_bounds__(256) void k_part2(const int* __restrict__ src,
                                               const int* __restrict__ dst,
                                               const int* __restrict__ cbase,
                                               const int* __restrict__ bucket_start,
                                               uint* __restrict__ bkt, int E) {
  __shared__ int lhist[256];
  __shared__ int lbase[256];
  int t = threadIdx.x;
  int cb = blockIdx.x * PART_CHUNK;
  lhist[t] = 0;
  __syncthreads();
  uint rec[16];
  short rb[16];
  short rr[16];
  #pragma unroll
  for (int i = 0; i < 16; i++) {
    int e = cb + i * 256 + t;
    if (e < E) {
      int s = src[e], d = dst[e];
      int b = d >> PART_SHIFT;
      rec[i] = ((uint)(d & (PART_NODES - 1)) << 17) | (uint)s;
      rb[i] = (short)b;
      rr[i] = (short)atomicAdd(&lhist[b], 1);
    } else rb[i] = -1;
  }
  __syncthreads();
  lbase[t] = cbase[blockIdx.x * 256 + t] + bucket_start[t];
  __syncthreads();
  #pragma unroll
  for (int i = 0; i < 16; i++) {
    if (rb[i] >= 0) bkt[lbase[rb[i]] + (int)rr[i]] = rec[i];
  }
}

// one block per bucket; LDS degree count + scan -> row_start + place col
__global__ __launch_bounds__(256) void k_fill4(const uint* __restrict__ bkt,
                                               const int* __restrict__ bucket_start,
                                               int* __restrict__ row_start,
                                               int* __restrict__ col, int n) {
  __shared__ int dcnt[PART_NODES];
  __shared__ int s[256];
  __shared__ int cur[PART_NODES];
  int t = threadIdx.x;
  int base = blockIdx.x << PART_SHIFT;
  dcnt[2 * t] = 0; dcnt[2 * t + 1] = 0;
  __syncthreads();
  int ebeg = bucket_start[blockIdx.x], eend = bucket_start[blockIdx.x + 1];
  for (int j = ebeg + t; j < eend; j += 256)
    atomicAdd(&dcnt[bkt[j] >> 17], 1);
  __syncthreads();
  int d0 = dcnt[2 * t], d1 = dcnt[2 * t + 1];
  int pair = d0 + d1;
  s[t] = pair;
  __syncthreads();
  for (int off = 1; off < 256; off <<= 1) {
    int u = (t >= off) ? s[t - off] : 0;
    __syncthreads();
    s[t] += u;
    __syncthreads();
  }
  int pre = ebeg + s[t] - pair;      // exclusive within bucket
  cur[2 * t] = pre;
  cur[2 * t + 1] = pre + d0;
  if (base + 2 * t < n)     row_start[base + 2 * t]     = pre;
  if (base + 2 * t + 1 < n) row_start[base + 2 * t + 1] = pre + d0;
  __syncthreads();
  for (int j = ebeg + t; j < eend; j += 256) {
    uint r = bkt[j];
    int pos = atomicAdd(&cur[r >> 17], 1);
    col[pos] = (int)(r & 0x1FFFFu);
  }
}

// ---------------- gather-mean (bf16 in/out, fp32 accum) ----------------
__global__ __launch_bounds__(256) void k_aggr_bf(const ushort* __restrict__ h,
                                                 const int* __restrict__ row_start,
                                                 const int* __restrict__ col,
                                                 ushort* __restrict__ aggr, int n) {
  int gw = (blockIdx.x * 256 + threadIdx.x) >> 6;
  int lane = threadIdx.x & 63;
  if (gw >= n) return;
  int beg = row_start[gw], end = row_start[gw + 1];
  int half = lane >> 5, sl = lane & 31;
  const ushort* hbase = h + (size_t)sl * 4;
  float a0 = 0.f, a1 = 0.f, a2 = 0.f, a3 = 0.f;

  for (int cb = beg; cb < end; cb += 64) {
    int idx = cb + lane;
    int cv = (idx < end) ? col[idx] : 0;
    int m = min(64, end - cb);
    int j = 0;
    for (; j + 8 <= m; j += 8) {         // 4 pairs (8 edges) in flight
      uint2 v0, v1, v2, v3;
      int s0 = __shfl(cv, j + 0 + half);
      int s1 = __shfl(cv, j + 2 + half);
      int s2 = __shfl(cv, j + 4 + half);
      int s3 = __shfl(cv, j + 6 + half);
      v0 = *(const uint2*)&hbase[(size_t)s0 * NF];
      v1 = *(const uint2*)&hbase[(size_t)s1 * NF];
      v2 = *(const uint2*)&hbase[(size_t)s2 * NF];
      v3 = *(const uint2*)&hbase[(size_t)s3 * NF];
      a0 += __uint_as_float(v0.x << 16) + __uint_as_float(v1.x << 16) +
            __uint_as_float(v2.x << 16) + __uint_as_float(v3.x << 16);
      a1 += __uint_as_float(v0.x & 0xffff0000u) + __uint_as_float(v1.x & 0xffff0000u) +
            __uint_as_float(v2.x & 0xffff0000u) + __uint_as_float(v3.x & 0xffff0000u);
      a2 += __uint_as_float(v0.y << 16) + __uint_as_float(v1.y << 16) +
            __uint_as_float(v2.y << 16) + __uint_as_float(v3.y << 16);
      a3 += __uint_as_float(v0.y & 0xffff0000u) + __uint_as_float(v1.y & 0xffff0000u) +
            __uint_as_float(v2.y & 0xffff0000u) + __uint_as_float(v3.y & 0xffff0000u);
    }
    for (; j < m; j += 2) {              // tail pairs (possibly odd last edge)
      int e = j + half;
      int s = __shfl(cv, (e < m) ? e : 0);
      if (e < m) {
        uint2 v = *(const uint2*)&hbase[(size_t)s * NF];
        a0 += __uint_as_float(v.x << 16);
        a1 += __uint_as_float(v.x & 0xffff0000u);
        a2 += __uint_as_float(v.y << 16);
        a3 += __uint_as_float(v.y & 0xffff0000u);
      }
    }
  }
  a0 += __shfl_xor(a0, 32);
  a1 += __shfl_xor(a1, 32);
  a2 += __shfl_xor(a2, 32);
  a3 += __shfl_xor(a3, 32);
  int d = end - beg;
  float inv = (d > 0) ? 1.0f / (float)d : 0.0f;
  if (half == 0) {
    uint2 o;
    o.x = (uint)f2bf(a0 * inv) | ((uint)f2bf(a1 * inv) << 16);
    o.y = (uint)f2bf(a2 * inv) | ((uint)f2bf(a3 * inv) << 16);
    *(uint2*)&aggr[(size_t)gw * NF + sl * 4] = o;
  }
}

// ---------------- MFMA GEMM (no LDS): hout = relu([aggr|hin] @ Wtg_l + b) ----------------
// B-frags loaded straight from pre-transposed global weights (L2-hot, 256B/thread).
__global__ __launch_bounds__(256) void k_gemm_mfma(const ushort* __restrict__ aggr,
                                                   const ushort* __restrict__ hin,
                                                   ushort* __restrict__ hout,
                                                   const ushort* __restrict__ Wtg,
                                                   const float* __restrict__ bias,
                                                   int n, int nslab) {
  int t = threadIdx.x;
  int wv = t >> 6, lane = t & 63;
  int c0 = wv * 32;
  int lrow = lane & 15, lhi = lane >> 4;

  // lane holds B[k = kc*32 + lhi*8 + j][col = c0 + ct*16 + lrow]
  bf16x8 bfrag[8][2];
  #pragma unroll
  for (int kc = 0; kc < 8; kc++)
    #pragma unroll
    for (int ct = 0; ct < 2; ct++) {
      int colv = c0 + ct * 16 + lrow;
      bfrag[kc][ct] = *(const bf16x8*)&Wtg[(size_t)colv * 256 + kc * 32 + lhi * 8];
    }
  float bv0 = bias[c0 + lrow], bv1 = bias[c0 + 16 + lrow];

  for (int sl = blockIdx.x; sl < nslab; sl += GEMM_BLOCKS) {
    int row0 = sl * 64;
    f32x4 acc[4][2];
    #pragma unroll
    for (int rt = 0; rt < 4; rt++)
      #pragma unroll
      for (int ct = 0; ct < 2; ct++) acc[rt][ct] = (f32x4){0.f, 0.f, 0.f, 0.f};

    #pragma unroll
    for (int kc = 0; kc < 8; kc++) {
      const ushort* Asrc = (kc < 4) ? aggr : hin;
      int k0 = (kc & 3) * 32 + lhi * 8;
      bf16x8 af[4];
      #pragma unroll
      for (int rt = 0; rt < 4; rt++) {
        int r = row0 + rt * 16 + lrow;
        if (r >= n) r = n - 1;
        af[rt] = *(const bf16x8*)&Asrc[(size_t)r * NF + k0];
      }
      #pragma unroll
      for (int rt = 0; rt < 4; rt++) {
        acc[rt][0] = __builtin_amdgcn_mfma_f32_16x16x32_bf16(af[rt], bfrag[kc][0], acc[rt][0], 0, 0, 0);
        acc[rt][1] = __builtin_amdgcn_mfma_f32_16x16x32_bf16(af[rt], bfrag[kc][1], acc[rt][1], 0, 0, 0);
      }
    }
    // C/D: col = lane&15, row = (lane>>4)*4 + reg   [m89-verified]
    #pragma unroll
    for (int rt = 0; rt < 4; rt++) {
      int rbase = row0 + rt * 16 + lhi * 4;
      #pragma unroll
      for (int r = 0; r < 4; r++) {
        int row = rbase + r;
        if (row < n) {
          hout[(size_t)row * NF + c0 + lrow]      = f2bf(fmaxf(acc[rt][0][r] + bv0, 0.f));
          hout[(size_t)row * NF + c0 + 16 + lrow] = f2bf(fmaxf(acc[rt][1][r] + bv1, 0.f));
        }
      }
    }
  }
}

// ---------------- pool + head ----------------
__global__ __launch_bounds__(128) void k_pool1(const ushort* __restrict__ h,
                                               float* __restrict__ partial, int n) {
  int f = threadIdx.x;
  float s = 0.f;
  for (int r = blockIdx.x; r < n; r += PB) s += b2f(h[(size_t)r * NF + f]);
  partial[blockIdx.x * NF + f] = s;
}

__global__ __launch_bounds__(128) void k_pool2(const float* __restrict__ partial,
                                               const float* __restrict__ Wg,
                                               const float* __restrict__ bg,
                                               float* __restrict__ out, int n) {
  __shared__ float g[NF];
  int f = threadIdx.x;
  float s = 0.f;
  for (int b = 0; b < PB; b++) s += partial[b * NF + f];
  g[f] = s / (float)n;
  __syncthreads();
  if (f < 64) {
    float z = bg[f];
    #pragma unroll 4
    for (int k = 0; k < NF; k++) z += g[k] * Wg[k * 64 + f];
    out[f] = 1.0f / (1.0f + expf(-z));
  }
}

// ---------------- launch ----------------
extern "C" void kernel_launch(void* const* d_in, const int* in_sizes, int n_in,
                              void* d_out, int out_size, void* d_ws, size_t ws_size,
                              hipStream_t stream) {
  const float* x   = (const float*)d_in[0];
  const int*   ei  = (const int*)d_in[1];
  const float* Wl1 = (const float*)d_in[2];
  const float* Wr1 = (const float*)d_in[3];
  const float* b1  = (const float*)d_in[4];
  const float* Wl2 = (const float*)d_in[5];
  const float* Wr2 = (const float*)d_in[6];
  const float* b2  = (const float*)d_in[7];
  const float* Wl3 = (const float*)d_in[8];
  const float* Wr3 = (const float*)d_in[9];
  const float* b3  = (const float*)d_in[10];
  const float* Wg  = (const float*)d_in[11];
  const float* bg  = (const float*)d_in[12];
  float* out = (float*)d_out;

  int n = in_sizes[0] / NF;      // 100000
  int E = in_sizes[1] / 2;       // 1600000
  const int* srcp = ei;
  const int* dstp = ei + E;

  char* w = (char*)d_ws;
  size_t off = 0;
  auto carve = [&](size_t bytes) -> void* {
    off = (off + 255) & ~(size_t)255;
    void* p = w + off;
    off += bytes;
    return p;
  };
  int nbkt  = (n + PART_NODES - 1) / PART_NODES;   // 196 coarse buckets
  int npart = (E + PART_CHUNK - 1) / PART_CHUNK;   // 391 chunks
  int*    col       = (int*)   carve((size_t)E * 4);
  int*    row_start = (int*)   carve((size_t)(n + 1) * 4);
  int*    bucket_start = (int*)carve((size_t)257 * 4);
  int*    btot      = (int*)   carve((size_t)256 * 4);
  int*    bcnt      = (int*)   carve((size_t)npart * 256 * 4);
  int*    cbase     = (int*)   carve((size_t)npart * 256 * 4);
  ushort* Wtg       = (ushort*)carve((size_t)3 * NF * 256 * 2);
  ushort* xb        = (ushort*)carve((size_t)n * NF * 2);
  ushort* aggr      = (ushort*)carve((size_t)n * NF * 2);
  ushort* ha        = (ushort*)carve((size_t)n * NF * 2);
  ushort* hb        = (ushort*)carve((size_t)n * NF * 2);
  float*  partial   = (float*) carve((size_t)PB * NF * 4);
  uint*   bkt       = (uint*)hb;   // 4B-packed staging aliases hb (dead until layer 2)

  int ag = (n + 3) / 4;
  int nslab = (n + 63) / 64;

  // convert x to bf16; prep transposed bf16 weights
  k_cvt<<<2048, 256, 0, stream>>>(x, xb, n * NF / 4);
  k_wprep<<<3 * NF, 256, 0, stream>>>(Wl1, Wr1, Wl2, Wr2, Wl3, Wr3, Wtg);

  // CSR build: chunk-histogram -> parallel 2D scan -> reserved scatter -> bucket-local fill
  k_part1<<<npart, 256, 0, stream>>>(dstp, bcnt, E);
  k_bscan1<<<256, 256, 0, stream>>>(bcnt, cbase, btot, npart);
  k_bscan2<<<1, 256, 0, stream>>>(btot, bucket_start, row_start, n, E);
  k_part2<<<npart, 256, 0, stream>>>(srcp, dstp, cbase, bucket_start, bkt, E);
  k_fill4<<<nbkt, 256, 0, stream>>>(bkt, bucket_start, row_start, col, n);

  // layer 1: xb -> ha
  k_aggr_bf<<<ag, 256, 0, stream>>>(xb, row_start, col, aggr, n);
  k_gemm_mfma<<<GEMM_BLOCKS, 256, 0, stream>>>(aggr, xb, ha, Wtg,            b1, n, nslab);
  // layer 2: ha -> hb
  k_aggr_bf<<<ag, 256, 0, stream>>>(ha, row_start, col, aggr, n);
  k_gemm_mfma<<<GEMM_BLOCKS, 256, 0, stream>>>(aggr, ha, hb, Wtg + NF * 256, b2, n, nslab);
  // layer 3: hb -> ha
  k_aggr_bf<<<ag, 256, 0, stream>>>(hb, row_start, col, aggr, n);
  k_gemm_mfma<<<GEMM_BLOCKS, 256, 0, stream>>>(aggr, hb, ha, Wtg + 2 * NF * 256, b3, n, nslab);

  // pool + head
  k_pool1<<<PB, 128, 0, stream>>>(ha, partial, n);
  k_pool2<<<1, 128, 0, stream>>>(partial, Wg, bg, out, n);
}